// Round 11
// baseline (323.641 us; speedup 1.0000x reference)
//
#include <hip/hip_runtime.h>
#include <math.h>

#define LL 256
#define DD 768
#define HH 384
#define G4 1536
#define NWIN 4
#define NLIN 9
#define NPOS 1024        // B*L
#define PROJ_N 12288     // 8 chains * 1536
#define HSTRIDE 520      // padded LDS ks-stride (BYTES now: fp8 H)
#define PSLOTS 33        // proj LDS ring slots (33 > 32-row live window)
#define DQ 0.00390625f   // 1/(16*16): undo W,H fp8 scaling

typedef __attribute__((ext_vector_type(8))) short short8;
typedef __attribute__((ext_vector_type(4))) short short4v;
typedef __attribute__((ext_vector_type(16))) float f32x16;

static __device__ __forceinline__ float bf2f(unsigned short u) {
    union { unsigned int i; float f; } v; v.i = ((unsigned int)u) << 16; return v.f;
}
static __device__ __forceinline__ unsigned short f2bf(float f) {
    unsigned int u = __float_as_uint(f);
    u += 0x7fff + ((u >> 16) & 1);   // round-to-nearest-even
    return (unsigned short)(u >> 16);
}
static __device__ __forceinline__ float fsig(float x) {
    return __builtin_amdgcn_rcpf(1.f + __expf(-x));
}
static __device__ __forceinline__ float ftanh(float x) {
    return 1.f - 2.f * __builtin_amdgcn_rcpf(1.f + __expf(2.f * x));
}
// f32 -> OCP e4m3fn, RNE, denorm, clamp 448. Hand-verified: 1.0->0x38,
// 2^-6->0x08, 448->0x7E, midpoint ties-to-even.
static __device__ __forceinline__ unsigned char f2e4m3(float f) {
    unsigned int u = __float_as_uint(f);
    const unsigned int sg = (u >> 24) & 0x80;
    u &= 0x7fffffff;
    if (u < 0x3C800000u) {            // |f| < 2^-6: denormal (step 2^-9)
        const float af = __uint_as_float(u);
        unsigned int d = (unsigned int)__float2uint_rn(af * 512.0f);
        return (unsigned char)(sg | (d > 8 ? 8u : d));   // d==8 == min normal
    }
    unsigned int r = u + 0x7ffff + ((u >> 20) & 1);      // RNE to 3-bit mant
    if (r > 0x43E00000u) r = 0x43E00000u;                // clamp to 448
    const int e = (int)(r >> 23) - 127;
    const unsigned int m = (r >> 20) & 7;
    return (unsigned char)(sg | ((unsigned int)(e + 7) << 3) | m);
}
static __device__ __forceinline__ float e4m32f(unsigned char b) {
    const int e = (b >> 3) & 15;
    const unsigned int m = b & 7;
    float f;
    if (e == 0) f = (float)m * 0.001953125f;             // denorm 2^-9 steps
    else f = __uint_as_float(((unsigned int)(e + 120) << 23) | (m << 20));
    return (b & 0x80) ? -f : f;
}

// ---------------------------------------------------------------- prep: scatter(+zero), weight casts, out-init
// HH weights now cast to fp8 e4m3 scaled x16 (same fragment geometry as
// bf16: 8 elems/lane per ks-slot, slot now 512 BYTES). IH stays bf16.
__global__ __launch_bounds__(256) void prep_kernel(
        const float* __restrict__ seq, const int* __restrict__ valid,
        unsigned short* __restrict__ xfrag,
        const float* __restrict__ wihF, const float* __restrict__ wihB,
        unsigned short* __restrict__ wfih,
        const float* __restrict__ whhF, const float* __restrict__ whhB,
        unsigned char* __restrict__ wfhh8,
        const float* __restrict__ lin_b, float* __restrict__ out) {
    const int tid = threadIdx.x;
    if (blockIdx.x < 128) {
        // ---------------- scatter + tail-zero (ballot-scan)
        const int b = blockIdx.x >> 5;
        const int chunk = blockIdx.x & 31;
        __shared__ int dest[LL];
        __shared__ int wsum[4];
        __shared__ int nvalid;
        const int v = valid[b * LL + tid];
        const unsigned long long m = __ballot(v != 0);
        const int lane = tid & 63, wvi = tid >> 6;
        const int pre = __popcll(m & (((unsigned long long)1 << lane) - 1));
        if (lane == 63) wsum[wvi] = pre + (v ? 1 : 0);
        __syncthreads();
        int base = 0;
#pragma unroll
        for (int k = 0; k < 4; ++k) if (k < wvi) base += wsum[k];
        dest[tid] = v ? (base + pre) : -1;
        if (tid == 0) nvalid = wsum[0] + wsum[1] + wsum[2] + wsum[3];
        __syncthreads();
        const int nv = nvalid;
        for (int l = chunk * 8; l < chunk * 8 + 8; ++l) {
            const int d = dest[l];
            if (d >= 0) {
                const float* src = seq + (size_t)(b * LL + l) * DD;
                const int pos = b * LL + d;
                const int pt = pos >> 5, pl = pos & 31;
                for (int j = tid; j < DD / 8; j += 256) {
                    const float4 v0 = ((const float4*)src)[2 * j];
                    const float4 v1 = ((const float4*)src)[2 * j + 1];
                    short8 pv;
                    pv[0] = (short)f2bf(v0.x); pv[1] = (short)f2bf(v0.y);
                    pv[2] = (short)f2bf(v0.z); pv[3] = (short)f2bf(v0.w);
                    pv[4] = (short)f2bf(v1.x); pv[5] = (short)f2bf(v1.y);
                    pv[6] = (short)f2bf(v1.z); pv[7] = (short)f2bf(v1.w);
                    *(short8*)(xfrag + ((size_t)(pt * 48 + (j >> 1)) * 512 + (pl + 32 * (j & 1)) * 8)) = pv;
                }
            }
            if (l >= nv) {   // dest slot l never written: zero its frag row
                const int pos = b * LL + l;
                const int pt = pos >> 5, pl = pos & 31;
                const short8 zv = {};
                for (int j = tid; j < DD / 8; j += 256)
                    *(short8*)(xfrag + ((size_t)(pt * 48 + (j >> 1)) * 512 + (pl + 32 * (j & 1)) * 8)) = zv;
            }
        }
    } else if (blockIdx.x < 896) {
        // ---------------- cast weights -> fragment layout
        __shared__ unsigned short lds[32 * 768];
        const int cb = blockIdx.x - 128;
        const int isIH = cb < 384;
        const int vblk = isIH ? cb : (cb - 384);
        const int K = isIH ? DD : HH;
        const float* srcF = isIH ? wihF : whhF;
        const float* srcB = isIH ? wihB : whhB;
        const int vrow0 = vblk * 32;
        const int chain = vrow0 / G4;
        const int dir = chain >> 2, wi = chain & 3;
        const float* src = (dir ? srcB : srcF) + (size_t)(wi * G4 + (vrow0 % G4)) * K;
        const int total = 32 * K;
        for (int i = tid * 4; i < total; i += 1024) {
            const float4 v = *(const float4*)(src + i);
            lds[i + 0] = f2bf(v.x); lds[i + 1] = f2bf(v.y);
            lds[i + 2] = f2bf(v.z); lds[i + 3] = f2bf(v.w);
        }
        __syncthreads();
        const int nks = K >> 4;
        for (int slot = tid; slot < nks * 64; slot += 256) {
            const int ks = slot >> 6;
            const int lane = slot & 63;
            const int row = lane & 31;
            const int kb = ks * 16 + (lane >> 5) * 8;
            if (isIH) {
                const short8 v = *(const short8*)&lds[row * K + kb];
                *(short8*)(wfih + ((size_t)vblk * nks + ks) * 512 + lane * 8) = v;
            } else {
                unsigned long long pk = 0;
#pragma unroll
                for (int j = 0; j < 8; ++j) {
                    const float f = bf2f(lds[row * K + kb + j]) * 16.f;   // x16 scale
                    pk |= (unsigned long long)f2e4m3(f) << (8 * j);
                }
                *(unsigned long long*)(wfhh8 + ((size_t)vblk * nks + ks) * 512 + lane * 8) = pk;
            }
        }
    } else {
        // ---------------- seed out with lin_b (attn_out2 atomicAdds partials)
        for (int i = tid; i < NPOS * NLIN; i += 256)
            out[i] = lin_b[i % NLIN];
    }
}

// ---------------------------------------------------------------- proj GEMM (MFMA, bf16 unchanged)
__global__ __launch_bounds__(256) void proj_mfma(
        const unsigned short* __restrict__ xf,
        const unsigned short* __restrict__ wf,
        const float* __restrict__ bihf, const float* __restrict__ bhhf,
        const float* __restrict__ bihb, const float* __restrict__ bhhb,
        unsigned short* __restrict__ proj) {
    __shared__ __align__(16) unsigned short st[4 * 4096];   // 32 KB
    const int wv = threadIdx.x >> 6;        // gate
    const int lane = threadIdx.x & 63;
    const int colid = lane & 31, hq = lane >> 5;
    const int chain = blockIdx.x & 7;       // XCD id
    const int r8 = blockIdx.x >> 3;         // 0..95
    const int us = r8 % 12;
    const int mtg = r8 / 12;                // 0..7
    const int dir = chain >> 2, wi = chain & 3;

    const unsigned short* bP = wf + (size_t)((chain * 48 + wv * 12 + us) * 48) * 512 + lane * 8;
    const unsigned short* aP = xf + (size_t)(mtg * 4 * 48) * 512 + lane * 8;

    f32x16 acc[4] = {};
#pragma unroll 4
    for (int ks = 0; ks < 48; ++ks) {
        const short8 bv = *(const short8*)(bP + ks * 512);
        const short8 a0 = *(const short8*)(aP + (0 * 48 + ks) * 512);
        const short8 a1 = *(const short8*)(aP + (1 * 48 + ks) * 512);
        const short8 a2 = *(const short8*)(aP + (2 * 48 + ks) * 512);
        const short8 a3 = *(const short8*)(aP + (3 * 48 + ks) * 512);
        acc[0] = __builtin_amdgcn_mfma_f32_32x32x16_bf16(a0, bv, acc[0], 0, 0, 0);
        acc[1] = __builtin_amdgcn_mfma_f32_32x32x16_bf16(a1, bv, acc[1], 0, 0, 0);
        acc[2] = __builtin_amdgcn_mfma_f32_32x32x16_bf16(a2, bv, acc[2], 0, 0, 0);
        acc[3] = __builtin_amdgcn_mfma_f32_32x32x16_bf16(a3, bv, acc[3], 0, 0, 0);
    }
    const int br = wv * HH + us * 32 + colid;
    const float bv = (dir ? bihb : bihf)[wi * G4 + br] + (dir ? bhhb : bhhf)[wi * G4 + br];
#pragma unroll
    for (int i = 0; i < 4; ++i) {
#pragma unroll
        for (int r = 0; r < 16; ++r) {
            const int row = (r & 3) + 8 * (r >> 2) + 4 * hq;
            st[i * 4096 + (row * 32 + colid) * 4 + wv] = f2bf(acc[i][r] + bv);
        }
    }
    __syncthreads();
#pragma unroll
    for (int j = 0; j < 8; ++j) {
        const int idx = j * 256 + threadIdx.x;
        const int i = idx >> 9, rem = idx & 511;
        const int pl = rem >> 4, q = rem & 15;
        const int pos = (mtg * 4 + i) * 32 + pl;
        *(int4*)(proj + (size_t)pos * PROJ_N + chain * G4 + us * 128 + q * 8) =
            ((const int4*)st)[idx];
    }
}

// ---------------------------------------------------------------- fused LSTM recurrence (fp8 recurrent path)
// MODEL (r10): step time is PER-CU L2->CU bandwidth on W: 1.18 MB/step @
// ~56 B/cyc = 8.8 us floor, measured 14.7. Explains r6 invariance (per-CU
// port, not shared) and why M=64 was neutral. Lever: halve W bytes.
// THIS ROUND: W_hh + H in fp8 e4m3 (x16 scale each; acc x 1/256), via
// mfma_f32_32x32x16_fp8_fp8 -- same K=16 / 8-elem-per-lane fragment
// geometry as the bf16 path (slots 512 BYTES), same instr count.
// proj/attn/hfin stay bf16; final h stored to hfin in full f32->bf16.
// FALSIFIED ledger: XCD remap(r1), reg W-pipe(r2), M=64(r4/5), launch
// bounds(r5), K-stagger(r6), two-pass(r8). CONFIRMED: ring(r10), NT-drop(r9).
__global__ __launch_bounds__(768, 1) void lstm_fused(
        const unsigned char* __restrict__ Wf8,
        const unsigned short* __restrict__ proj,
        unsigned short* __restrict__ hfin) {
    const int p = blockIdx.x & 3, sub = (blockIdx.x >> 2) & 1;
    const int slot = blockIdx.x >> 3;
    const int chainA[4] = {3, 7, 2, 6};   // w=9,9,7,7
    const int chainB[4] = {0, 4, 1, 5};   // w=3,3,5,5
    const int chain = (slot < 16) ? chainA[p] : chainB[p];
    const int pt = sub * 16 + (slot & 15);
    const int dir = chain >> 2, wi = chain & 3;
    const int w = 3 + 2 * wi, half = wi + 1;
    const int tid = threadIdx.x;
    const int lane = tid & 63, wv = tid >> 6;   // wv 0..11 = unit slice
    const int colid = lane & 31, hq = lane >> 5;
    const int uu = wv * 32 + colid;
    const int m0 = pt * 32, b = m0 >> 8, l0 = m0 & 255;

    __shared__ __align__(16) unsigned char Hbuf[2][24 * HSTRIDE];    // 25 KB (fp8)
    __shared__ __align__(16) unsigned short Pring[PSLOTS][1536];     // 101.4 KB
    float c[16];
#pragma unroll
    for (int r = 0; r < 16; ++r) c[r] = 0.f;

    const unsigned int* projU = (const unsigned int*)(proj
        + (size_t)(b * LL) * PROJ_N + chain * G4);
    const unsigned char* Wb = Wf8 + (size_t)((chain * 48 + wv) * 24) * 512 + lane * 8;
    const int ksp = uu >> 4, khp = (uu >> 3) & 1, jp = uu & 7;
    const int hslot = ksp * HSTRIDE + khp * 256 + jp;   // byte offsets (+ row*8)
    unsigned short* ho = hfin + (size_t)chain * (NPOS * HH) + (size_t)pt * 12288;

    // ---- preload step-0's 32-row window into the ring
    const int t0 = dir ? (w - 1) : 0;
    for (int i = 0; i < 32; ++i) {
        int src = l0 + i + t0 - half;
        src = src < 0 ? 0 : (src > LL - 1 ? LL - 1 : src);
        ((unsigned int*)&Pring[src % PSLOTS][0])[tid] =
            projU[(size_t)src * (PROJ_N / 2) + tid];
    }
    __syncthreads();

    for (int s = 0; s < w; ++s) {
        const int t = dir ? (w - 1 - s) : s;
        const int tmh = t - half;
        unsigned char* cur = Hbuf[s & 1];
        const unsigned char* prev = Hbuf[(s & 1) ^ 1];

        // ---- issue next step's single new row early (hidden under MFMA)
        int nsrc = -1;
        unsigned int pref = 0;
        if (s + 1 < w) {
            const int tn = dir ? (w - 2 - s) : (s + 1);
            nsrc = dir ? (l0 + tn - half) : (l0 + 31 + tn - half);
            nsrc = nsrc < 0 ? 0 : (nsrc > LL - 1 ? LL - 1 : nsrc);
            pref = projU[(size_t)nsrc * (PROJ_N / 2) + tid];
        }

        f32x16 acc0 = {}, acc1 = {}, acc2 = {}, acc3 = {};
        if (s > 0) {   // s==0: H is zero, gates = proj only
            const unsigned char* Alds = prev + lane * 8;
#pragma unroll 4
            for (int ks = 0; ks < 24; ++ks) {
                const long av  = *(const long*)(Alds + ks * HSTRIDE);
                const long bv0 = *(const long*)(Wb + (size_t)(0 * 288 + ks) * 512);
                const long bv1 = *(const long*)(Wb + (size_t)(1 * 288 + ks) * 512);
                const long bv2 = *(const long*)(Wb + (size_t)(2 * 288 + ks) * 512);
                const long bv3 = *(const long*)(Wb + (size_t)(3 * 288 + ks) * 512);
                acc0 = __builtin_amdgcn_mfma_f32_32x32x16_fp8_fp8(av, bv0, acc0, 0, 0, 0);
                acc1 = __builtin_amdgcn_mfma_f32_32x32x16_fp8_fp8(av, bv1, acc1, 0, 0, 0);
                acc2 = __builtin_amdgcn_mfma_f32_32x32x16_fp8_fp8(av, bv2, acc2, 0, 0, 0);
                acc3 = __builtin_amdgcn_mfma_f32_32x32x16_fp8_fp8(av, bv3, acc3, 0, 0, 0);
            }
        }

#pragma unroll
        for (int r = 0; r < 16; ++r) {
            const int row = (r & 3) + 8 * (r >> 2) + 4 * hq;
            const int src = l0 + row + tmh;
            const int cs = src < 0 ? 0 : (src > LL - 1 ? LL - 1 : src);
            unsigned char hv;
            if (src >= 0 && src < LL) {
                const short4v pj = *(const short4v*)&Pring[cs % PSLOTS][uu * 4];
                const float gi = acc0[r] * DQ + bf2f((unsigned short)pj[0]);
                const float gf = acc1[r] * DQ + bf2f((unsigned short)pj[1]);
                const float gg = acc2[r] * DQ + bf2f((unsigned short)pj[2]);
                const float go = acc3[r] * DQ + bf2f((unsigned short)pj[3]);
                c[r] = fsig(gf) * c[r] + fsig(gi) * ftanh(gg);
                const float h = fsig(go) * ftanh(c[r]);
                hv = f2e4m3(h * 16.f);
                if (s == w - 1)   // final h to hfin in full precision
                    ho[ksp * 512 + khp * 256 + jp + row * 8] = f2bf(h);
            } else {
                hv = (s == 0) ? (unsigned char)0 : prev[hslot + row * 8];
                if (s == w - 1)
                    ho[ksp * 512 + khp * 256 + jp + row * 8] =
                        f2bf(e4m32f(hv) * 0.0625f);
            }
            cur[hslot + row * 8] = hv;
        }

        // ---- commit prefetched row (identical bytes if clamp-duplicate)
        if (nsrc >= 0)
            ((unsigned int*)&Pring[nsrc % PSLOTS][0])[tid] = pref;
        __syncthreads();   // Hbuf + Pring writes visible for next step
    }
}

// ---------------------------------------------------------------- attention, stage 1: partial scores
__global__ __launch_bounds__(192) void attn_scores_kernel(
        const unsigned short* __restrict__ xfrag,
        const unsigned short* __restrict__ hfin,
        float* __restrict__ scores) {
    const int pt = blockIdx.x >> 3, seg = blockIdx.x & 7;
    const int dir = seg >> 2, q = seg & 3;
    const int tid = threadIdx.x;
    const int lane = tid & 63, wv3 = tid >> 6;
    const int pos = lane & 31;
    __shared__ float scp[3][4][32];

    const unsigned short* xb = xfrag + ((size_t)(pt * 48 + 24 * dir)) * 512 + lane * 8;
    const unsigned short* hb0 = hfin + (size_t)(dir * 4) * (NPOS * HH) + (size_t)pt * 12288 + lane * 8;

    float sc4[4] = {0.f, 0.f, 0.f, 0.f};
#pragma unroll
    for (int k = 0; k < 2; ++k) {
        const int ks = q * 6 + wv3 * 2 + k;
        const short8 xv = *(const short8*)(xb + ks * 512);
        float xf[8];
#pragma unroll
        for (int j = 0; j < 8; ++j) xf[j] = bf2f((unsigned short)xv[j]);
#pragma unroll
        for (int wi = 0; wi < 4; ++wi) {
            const short8 hv = *(const short8*)(hb0 + (size_t)wi * (NPOS * HH) + ks * 512);
#pragma unroll
            for (int j = 0; j < 8; ++j)
                sc4[wi] = fmaf(xf[j], bf2f((unsigned short)hv[j]), sc4[wi]);
        }
    }
#pragma unroll
    for (int wi = 0; wi < 4; ++wi) sc4[wi] += __shfl_down(sc4[wi], 32);
    if (lane < 32) {
#pragma unroll
        for (int wi = 0; wi < 4; ++wi) scp[wv3][wi][pos] = sc4[wi];
    }
    __syncthreads();
    if (tid < 32) {
#pragma unroll
        for (int wi = 0; wi < 4; ++wi) {
            const float v = scp[0][wi][tid] + scp[1][wi][tid] + scp[2][wi][tid];
            scores[(((size_t)pt * 8 + seg) * 4 + wi) * 32 + tid] = v;
        }
    }
}

// ---------------------------------------------------------------- attention, stage 2: softmax + output
__global__ __launch_bounds__(192) void attn_out2_kernel(
        const unsigned short* __restrict__ xfrag,
        const unsigned short* __restrict__ hfin,
        const float* __restrict__ scores,
        const float* __restrict__ lin_w,
        float* __restrict__ out) {
    const int pt = blockIdx.x >> 3, seg = blockIdx.x & 7;
    const int dir = seg >> 2, q = seg & 3;
    const int tid = threadIdx.x;
    const int lane = tid & 63, wv3 = tid >> 6;
    const int pos = lane & 31, kh = lane >> 5;
    const float inv_sqrt_d = 0.03608439182435161f;
    __shared__ float redp[3][32][10];

    float s[4];
#pragma unroll
    for (int wi = 0; wi < 4; ++wi) {
        float v = 0.f;
#pragma unroll
        for (int s2 = 0; s2 < 8; ++s2)
            v += scores[(((size_t)pt * 8 + s2) * 4 + wi) * 32 + pos];
        s[wi] = v * inv_sqrt_d;
    }
    float mx = fmaxf(fmaxf(s[0], s[1]), fmaxf(s[2], s[3]));
    float denom = 0.f;
    float aw[4];
#pragma unroll
    for (int wi = 0; wi < 4; ++wi) { aw[wi] = __expf(s[wi] - mx); denom += aw[wi]; }
    const float rd = __builtin_amdgcn_rcpf(denom);
#pragma unroll
    for (int wi = 0; wi < 4; ++wi) aw[wi] *= rd;

    const unsigned short* xb = xfrag + ((size_t)(pt * 48 + 24 * dir)) * 512 + lane * 8;
    const unsigned short* hb0 = hfin + (size_t)(dir * 4) * (NPOS * HH) + (size_t)pt * 12288 + lane * 8;

    float rp[9];
#pragma unroll
    for (int r = 0; r < 9; ++r) rp[r] = 0.f;
#pragma unroll
    for (int k = 0; k < 2; ++k) {
        const int ks = q * 6 + wv3 * 2 + k;
        const short8 xv = *(const short8*)(xb + ks * 512);
        float ov[8];
#pragma unroll
        for (int j = 0; j < 8; ++j) ov[j] = bf2f((unsigned short)xv[j]);
#pragma unroll
        for (int wi = 0; wi < 4; ++wi) {
            const short8 hv = *(const short8*)(hb0 + (size_t)wi * (NPOS * HH) + ks * 512);
#pragma unroll
            for (int j = 0; j < 8; ++j)
                ov[j] = fmaf(aw[wi], bf2f((unsigned short)hv[j]), ov[j]);
        }
        const int dbase = dir * 384 + ks * 16 + kh * 8;
#pragma unroll
        for (int r = 0; r < 9; ++r) {
            const float4 lw0 = *(const float4*)(lin_w + r * DD + dbase);
            const float4 lw1 = *(const float4*)(lin_w + r * DD + dbase + 4);
            rp[r] += ov[0] * lw0.x + ov[1] * lw0.y + ov[2] * lw0.z + ov[3] * lw0.w
                   + ov[4] * lw1.x + ov[5] * lw1.y + ov[6] * lw1.z + ov[7] * lw1.w;
        }
    }
#pragma unroll
    for (int r = 0; r < 9; ++r) rp[r] += __shfl_down(rp[r], 32);
    if (lane < 32) {
#pragma unroll
        for (int r = 0; r < 9; ++r) redp[wv3][pos][r] = rp[r];
    }
    __syncthreads();
    if (tid < 96) {
#pragma unroll
        for (int e = 0; e < 3; ++e) {
            const int flat = tid * 3 + e;
            const int p2 = flat / 9, r = flat % 9;
            const float sum = redp[0][p2][r] + redp[1][p2][r] + redp[2][p2][r];
            atomicAdd(&out[(size_t)(pt * 32 + p2) * NLIN + r], sum);
        }
    }
}

// ---------------------------------------------------------------- launch
extern "C" void kernel_launch(void* const* d_in, const int* in_sizes, int n_in,
                              void* d_out, int out_size, void* d_ws, size_t ws_size,
                              hipStream_t stream) {
    (void)in_sizes; (void)n_in; (void)out_size; (void)ws_size;
    const float* seq   = (const float*)d_in[0];
    const int*   valid = (const int*)d_in[1];
    const float* wih_f = (const float*)d_in[2];
    const float* whh_f = (const float*)d_in[3];
    const float* bih_f = (const float*)d_in[4];
    const float* bhh_f = (const float*)d_in[5];
    const float* wih_b = (const float*)d_in[6];
    const float* whh_b = (const float*)d_in[7];
    const float* bih_b = (const float*)d_in[8];
    const float* bhh_b = (const float*)d_in[9];
    const float* lin_w = (const float*)d_in[10];
    const float* lin_b = (const float*)d_in[11];
    float* out = (float*)d_out;

    // workspace layout (~61.5 MB; wfhh region now holds fp8 bytes, underused)
    unsigned short* xfrag = (unsigned short*)d_ws;                 // 786432 bf16
    unsigned short* proj  = xfrag + (size_t)NPOS * DD;             // 12582912 bf16
    unsigned short* wfhh  = proj + (size_t)NPOS * PROJ_N;          // region (fp8 uses half)
    unsigned short* wfih  = wfhh + (size_t)4718592;                // 9437184 bf16
    unsigned short* hfin  = wfih + (size_t)9437184;                // 3145728 bf16
    float* scores = (float*)(hfin + (size_t)3145728);              // 128 KB

    prep_kernel<<<897, 256, 0, stream>>>(seq, valid, xfrag,
                                         wih_f, wih_b, wfih,
                                         whh_f, whh_b, (unsigned char*)wfhh,
                                         lin_b, out);
    proj_mfma<<<768, 256, 0, stream>>>(xfrag, wfih, bih_f, bhh_f, bih_b, bhh_b, proj);
    lstm_fused<<<256, 768, 0, stream>>>((const unsigned char*)wfhh, proj, hfin);
    attn_scores_kernel<<<256, 192, 0, stream>>>(xfrag, hfin, scores);
    attn_out2_kernel<<<256, 192, 0, stream>>>(xfrag, hfin, scores, lin_w, out);
}

// Round 12
// 323.103 us; speedup vs baseline: 1.0017x; 1.0017x over previous
//
#include <hip/hip_runtime.h>
#include <math.h>

#define LL 256
#define DD 768
#define HH 384
#define G4 1536
#define NWIN 4
#define NLIN 9
#define NPOS 1024        // B*L
#define PROJ_N 12288     // 8 chains * 1536
#define HSTRIDE 520      // padded LDS ks-stride (BYTES: fp8 H)
#define PSLOTS 33        // proj LDS ring slots (33 > 32-row live window)
#define DQ 0.00390625f   // 1/(16*16): undo W,H fp8 scaling

typedef __attribute__((ext_vector_type(8))) short short8;
typedef __attribute__((ext_vector_type(4))) short short4v;
typedef __attribute__((ext_vector_type(16))) float f32x16;

static __device__ __forceinline__ float bf2f(unsigned short u) {
    union { unsigned int i; float f; } v; v.i = ((unsigned int)u) << 16; return v.f;
}
static __device__ __forceinline__ unsigned short f2bf(float f) {
    unsigned int u = __float_as_uint(f);
    u += 0x7fff + ((u >> 16) & 1);   // round-to-nearest-even
    return (unsigned short)(u >> 16);
}
static __device__ __forceinline__ float fsig(float x) {
    return __builtin_amdgcn_rcpf(1.f + __expf(-x));
}
static __device__ __forceinline__ float ftanh(float x) {
    return 1.f - 2.f * __builtin_amdgcn_rcpf(1.f + __expf(2.f * x));
}
// f32 -> OCP e4m3fn soft convert (prep only -- NOT in the hot loop).
static __device__ __forceinline__ unsigned char f2e4m3(float f) {
    unsigned int u = __float_as_uint(f);
    const unsigned int sg = (u >> 24) & 0x80;
    u &= 0x7fffffff;
    if (u < 0x3C800000u) {            // |f| < 2^-6: denormal (step 2^-9)
        const float af = __uint_as_float(u);
        unsigned int d = (unsigned int)__float2uint_rn(af * 512.0f);
        return (unsigned char)(sg | (d > 8 ? 8u : d));   // d==8 == min normal
    }
    unsigned int r = u + 0x7ffff + ((u >> 20) & 1);      // RNE to 3-bit mant
    if (r > 0x43E00000u) r = 0x43E00000u;                // clamp to 448
    const int e = (int)(r >> 23) - 127;
    const unsigned int m = (r >> 20) & 7;
    return (unsigned char)(sg | ((unsigned int)(e + 7) << 3) | m);
}
static __device__ __forceinline__ float e4m32f(unsigned char b) {
    const int e = (b >> 3) & 15;
    const unsigned int m = b & 7;
    float f;
    if (e == 0) f = (float)m * 0.001953125f;             // denorm 2^-9 steps
    else f = __uint_as_float(((unsigned int)(e + 120) << 23) | (m << 20));
    return (b & 0x80) ? -f : f;
}

// ---------------------------------------------------------------- prep: scatter(+zero), weight casts, out-init
__global__ __launch_bounds__(256) void prep_kernel(
        const float* __restrict__ seq, const int* __restrict__ valid,
        unsigned short* __restrict__ xfrag,
        const float* __restrict__ wihF, const float* __restrict__ wihB,
        unsigned short* __restrict__ wfih,
        const float* __restrict__ whhF, const float* __restrict__ whhB,
        unsigned char* __restrict__ wfhh8,
        const float* __restrict__ lin_b, float* __restrict__ out) {
    const int tid = threadIdx.x;
    if (blockIdx.x < 128) {
        // ---------------- scatter + tail-zero (ballot-scan)
        const int b = blockIdx.x >> 5;
        const int chunk = blockIdx.x & 31;
        __shared__ int dest[LL];
        __shared__ int wsum[4];
        __shared__ int nvalid;
        const int v = valid[b * LL + tid];
        const unsigned long long m = __ballot(v != 0);
        const int lane = tid & 63, wvi = tid >> 6;
        const int pre = __popcll(m & (((unsigned long long)1 << lane) - 1));
        if (lane == 63) wsum[wvi] = pre + (v ? 1 : 0);
        __syncthreads();
        int base = 0;
#pragma unroll
        for (int k = 0; k < 4; ++k) if (k < wvi) base += wsum[k];
        dest[tid] = v ? (base + pre) : -1;
        if (tid == 0) nvalid = wsum[0] + wsum[1] + wsum[2] + wsum[3];
        __syncthreads();
        const int nv = nvalid;
        for (int l = chunk * 8; l < chunk * 8 + 8; ++l) {
            const int d = dest[l];
            if (d >= 0) {
                const float* src = seq + (size_t)(b * LL + l) * DD;
                const int pos = b * LL + d;
                const int pt = pos >> 5, pl = pos & 31;
                for (int j = tid; j < DD / 8; j += 256) {
                    const float4 v0 = ((const float4*)src)[2 * j];
                    const float4 v1 = ((const float4*)src)[2 * j + 1];
                    short8 pv;
                    pv[0] = (short)f2bf(v0.x); pv[1] = (short)f2bf(v0.y);
                    pv[2] = (short)f2bf(v0.z); pv[3] = (short)f2bf(v0.w);
                    pv[4] = (short)f2bf(v1.x); pv[5] = (short)f2bf(v1.y);
                    pv[6] = (short)f2bf(v1.z); pv[7] = (short)f2bf(v1.w);
                    *(short8*)(xfrag + ((size_t)(pt * 48 + (j >> 1)) * 512 + (pl + 32 * (j & 1)) * 8)) = pv;
                }
            }
            if (l >= nv) {   // dest slot l never written: zero its frag row
                const int pos = b * LL + l;
                const int pt = pos >> 5, pl = pos & 31;
                const short8 zv = {};
                for (int j = tid; j < DD / 8; j += 256)
                    *(short8*)(xfrag + ((size_t)(pt * 48 + (j >> 1)) * 512 + (pl + 32 * (j & 1)) * 8)) = zv;
            }
        }
    } else if (blockIdx.x < 896) {
        // ---------------- cast weights -> fragment layout (HH -> fp8 x16)
        __shared__ unsigned short lds[32 * 768];
        const int cb = blockIdx.x - 128;
        const int isIH = cb < 384;
        const int vblk = isIH ? cb : (cb - 384);
        const int K = isIH ? DD : HH;
        const float* srcF = isIH ? wihF : whhF;
        const float* srcB = isIH ? wihB : whhB;
        const int vrow0 = vblk * 32;
        const int chain = vrow0 / G4;
        const int dir = chain >> 2, wi = chain & 3;
        const float* src = (dir ? srcB : srcF) + (size_t)(wi * G4 + (vrow0 % G4)) * K;
        const int total = 32 * K;
        for (int i = tid * 4; i < total; i += 1024) {
            const float4 v = *(const float4*)(src + i);
            lds[i + 0] = f2bf(v.x); lds[i + 1] = f2bf(v.y);
            lds[i + 2] = f2bf(v.z); lds[i + 3] = f2bf(v.w);
        }
        __syncthreads();
        const int nks = K >> 4;
        for (int slot = tid; slot < nks * 64; slot += 256) {
            const int ks = slot >> 6;
            const int lane = slot & 63;
            const int row = lane & 31;
            const int kb = ks * 16 + (lane >> 5) * 8;
            if (isIH) {
                const short8 v = *(const short8*)&lds[row * K + kb];
                *(short8*)(wfih + ((size_t)vblk * nks + ks) * 512 + lane * 8) = v;
            } else {
                unsigned long long pk = 0;
#pragma unroll
                for (int j = 0; j < 8; ++j) {
                    const float f = bf2f(lds[row * K + kb + j]) * 16.f;   // x16 scale
                    pk |= (unsigned long long)f2e4m3(f) << (8 * j);
                }
                *(unsigned long long*)(wfhh8 + ((size_t)vblk * nks + ks) * 512 + lane * 8) = pk;
            }
        }
    } else {
        // ---------------- seed out with lin_b (attn_out2 atomicAdds partials)
        for (int i = tid; i < NPOS * NLIN; i += 256)
            out[i] = lin_b[i % NLIN];
    }
}

// ---------------------------------------------------------------- proj GEMM (MFMA, bf16 unchanged)
__global__ __launch_bounds__(256) void proj_mfma(
        const unsigned short* __restrict__ xf,
        const unsigned short* __restrict__ wf,
        const float* __restrict__ bihf, const float* __restrict__ bhhf,
        const float* __restrict__ bihb, const float* __restrict__ bhhb,
        unsigned short* __restrict__ proj) {
    __shared__ __align__(16) unsigned short st[4 * 4096];   // 32 KB
    const int wv = threadIdx.x >> 6;        // gate
    const int lane = threadIdx.x & 63;
    const int colid = lane & 31, hq = lane >> 5;
    const int chain = blockIdx.x & 7;       // XCD id
    const int r8 = blockIdx.x >> 3;         // 0..95
    const int us = r8 % 12;
    const int mtg = r8 / 12;                // 0..7
    const int dir = chain >> 2, wi = chain & 3;

    const unsigned short* bP = wf + (size_t)((chain * 48 + wv * 12 + us) * 48) * 512 + lane * 8;
    const unsigned short* aP = xf + (size_t)(mtg * 4 * 48) * 512 + lane * 8;

    f32x16 acc[4] = {};
#pragma unroll 4
    for (int ks = 0; ks < 48; ++ks) {
        const short8 bv = *(const short8*)(bP + ks * 512);
        const short8 a0 = *(const short8*)(aP + (0 * 48 + ks) * 512);
        const short8 a1 = *(const short8*)(aP + (1 * 48 + ks) * 512);
        const short8 a2 = *(const short8*)(aP + (2 * 48 + ks) * 512);
        const short8 a3 = *(const short8*)(aP + (3 * 48 + ks) * 512);
        acc[0] = __builtin_amdgcn_mfma_f32_32x32x16_bf16(a0, bv, acc[0], 0, 0, 0);
        acc[1] = __builtin_amdgcn_mfma_f32_32x32x16_bf16(a1, bv, acc[1], 0, 0, 0);
        acc[2] = __builtin_amdgcn_mfma_f32_32x32x16_bf16(a2, bv, acc[2], 0, 0, 0);
        acc[3] = __builtin_amdgcn_mfma_f32_32x32x16_bf16(a3, bv, acc[3], 0, 0, 0);
    }
    const int br = wv * HH + us * 32 + colid;
    const float bv = (dir ? bihb : bihf)[wi * G4 + br] + (dir ? bhhb : bhhf)[wi * G4 + br];
#pragma unroll
    for (int i = 0; i < 4; ++i) {
#pragma unroll
        for (int r = 0; r < 16; ++r) {
            const int row = (r & 3) + 8 * (r >> 2) + 4 * hq;
            st[i * 4096 + (row * 32 + colid) * 4 + wv] = f2bf(acc[i][r] + bv);
        }
    }
    __syncthreads();
#pragma unroll
    for (int j = 0; j < 8; ++j) {
        const int idx = j * 256 + threadIdx.x;
        const int i = idx >> 9, rem = idx & 511;
        const int pl = rem >> 4, q = rem & 15;
        const int pos = (mtg * 4 + i) * 32 + pl;
        *(int4*)(proj + (size_t)pos * PROJ_N + chain * G4 + us * 128 + q * 8) =
            ((const int4*)st)[idx];
    }
}

// ---------------------------------------------------------------- fused LSTM recurrence (fp8, HW cvt epilogue)
// r11 POST-MORTEM: fp8 passed (absmax 0.03125, fragment layout verified)
// but soft f2e4m3 in the epilogue (16 branchy calls/thread/step, lane-
// divergent denormal path) cost ~9 us/step -- more than the W-byte saving.
// THIS ROUND: identical to r11 except the epilogue converts h via
// __builtin_amdgcn_cvt_pk_fp8_f32 (HW packed f32->OCP e4m3, RNE,
// saturating, branch-free): 8 instrs replace ~500 VALU.
// FALSIFIED ledger: XCD remap(r1), reg W-pipe(r2), M=64(r4/5),
// launch_bounds(r5), K-stagger(r6), two-pass(r8), soft-cvt fp8(r11).
// CONFIRMED: NT-drop(r9), proj LDS ring(r10).
// Gate: lstm >=128 us => fp8 dead, revert to r10 next round.
__global__ __launch_bounds__(768, 1) void lstm_fused(
        const unsigned char* __restrict__ Wf8,
        const unsigned short* __restrict__ proj,
        unsigned short* __restrict__ hfin) {
    const int p = blockIdx.x & 3, sub = (blockIdx.x >> 2) & 1;
    const int slot = blockIdx.x >> 3;
    const int chainA[4] = {3, 7, 2, 6};   // w=9,9,7,7
    const int chainB[4] = {0, 4, 1, 5};   // w=3,3,5,5
    const int chain = (slot < 16) ? chainA[p] : chainB[p];
    const int pt = sub * 16 + (slot & 15);
    const int dir = chain >> 2, wi = chain & 3;
    const int w = 3 + 2 * wi, half = wi + 1;
    const int tid = threadIdx.x;
    const int lane = tid & 63, wv = tid >> 6;   // wv 0..11 = unit slice
    const int colid = lane & 31, hq = lane >> 5;
    const int uu = wv * 32 + colid;
    const int m0 = pt * 32, b = m0 >> 8, l0 = m0 & 255;

    __shared__ __align__(16) unsigned char Hbuf[2][24 * HSTRIDE];    // 25 KB (fp8)
    __shared__ __align__(16) unsigned short Pring[PSLOTS][1536];     // 101.4 KB
    float c[16];
#pragma unroll
    for (int r = 0; r < 16; ++r) c[r] = 0.f;

    const unsigned int* projU = (const unsigned int*)(proj
        + (size_t)(b * LL) * PROJ_N + chain * G4);
    const unsigned char* Wb = Wf8 + (size_t)((chain * 48 + wv) * 24) * 512 + lane * 8;
    const int ksp = uu >> 4, khp = (uu >> 3) & 1, jp = uu & 7;
    const int hslot = ksp * HSTRIDE + khp * 256 + jp;   // byte offsets (+ row*8)
    unsigned short* ho = hfin + (size_t)chain * (NPOS * HH) + (size_t)pt * 12288;

    // ---- preload step-0's 32-row window into the ring
    const int t0 = dir ? (w - 1) : 0;
    for (int i = 0; i < 32; ++i) {
        int src = l0 + i + t0 - half;
        src = src < 0 ? 0 : (src > LL - 1 ? LL - 1 : src);
        ((unsigned int*)&Pring[src % PSLOTS][0])[tid] =
            projU[(size_t)src * (PROJ_N / 2) + tid];
    }
    __syncthreads();

    for (int s = 0; s < w; ++s) {
        const int t = dir ? (w - 1 - s) : s;
        const int tmh = t - half;
        unsigned char* cur = Hbuf[s & 1];
        const unsigned char* prev = Hbuf[(s & 1) ^ 1];

        // ---- issue next step's single new row early (hidden under MFMA)
        int nsrc = -1;
        unsigned int pref = 0;
        if (s + 1 < w) {
            const int tn = dir ? (w - 2 - s) : (s + 1);
            nsrc = dir ? (l0 + tn - half) : (l0 + 31 + tn - half);
            nsrc = nsrc < 0 ? 0 : (nsrc > LL - 1 ? LL - 1 : nsrc);
            pref = projU[(size_t)nsrc * (PROJ_N / 2) + tid];
        }

        f32x16 acc0 = {}, acc1 = {}, acc2 = {}, acc3 = {};
        if (s > 0) {   // s==0: H is zero, gates = proj only
            const unsigned char* Alds = prev + lane * 8;
#pragma unroll 4
            for (int ks = 0; ks < 24; ++ks) {
                const long av  = *(const long*)(Alds + ks * HSTRIDE);
                const long bv0 = *(const long*)(Wb + (size_t)(0 * 288 + ks) * 512);
                const long bv1 = *(const long*)(Wb + (size_t)(1 * 288 + ks) * 512);
                const long bv2 = *(const long*)(Wb + (size_t)(2 * 288 + ks) * 512);
                const long bv3 = *(const long*)(Wb + (size_t)(3 * 288 + ks) * 512);
                acc0 = __builtin_amdgcn_mfma_f32_32x32x16_fp8_fp8(av, bv0, acc0, 0, 0, 0);
                acc1 = __builtin_amdgcn_mfma_f32_32x32x16_fp8_fp8(av, bv1, acc1, 0, 0, 0);
                acc2 = __builtin_amdgcn_mfma_f32_32x32x16_fp8_fp8(av, bv2, acc2, 0, 0, 0);
                acc3 = __builtin_amdgcn_mfma_f32_32x32x16_fp8_fp8(av, bv3, acc3, 0, 0, 0);
            }
        }

#pragma unroll
        for (int r2 = 0; r2 < 16; r2 += 2) {
            float hf0 = 0.f, hf1 = 0.f;
            unsigned char alt0 = 0, alt1 = 0;
            bool in0, in1;
            {   // element r2
                const int r = r2;
                const int row = (r & 3) + 8 * (r >> 2) + 4 * hq;
                const int src = l0 + row + tmh;
                const int cs = src < 0 ? 0 : (src > LL - 1 ? LL - 1 : src);
                in0 = (src >= 0 && src < LL);
                if (in0) {
                    const short4v pj = *(const short4v*)&Pring[cs % PSLOTS][uu * 4];
                    const float gi = fmaf(acc0[r], DQ, bf2f((unsigned short)pj[0]));
                    const float gf = fmaf(acc1[r], DQ, bf2f((unsigned short)pj[1]));
                    const float gg = fmaf(acc2[r], DQ, bf2f((unsigned short)pj[2]));
                    const float go = fmaf(acc3[r], DQ, bf2f((unsigned short)pj[3]));
                    c[r] = fsig(gf) * c[r] + fsig(gi) * ftanh(gg);
                    hf0 = fsig(go) * ftanh(c[r]);
                } else if (s > 0) {
                    alt0 = prev[hslot + row * 8];
                }
            }
            {   // element r2+1
                const int r = r2 + 1;
                const int row = (r & 3) + 8 * (r >> 2) + 4 * hq;
                const int src = l0 + row + tmh;
                const int cs = src < 0 ? 0 : (src > LL - 1 ? LL - 1 : src);
                in1 = (src >= 0 && src < LL);
                if (in1) {
                    const short4v pj = *(const short4v*)&Pring[cs % PSLOTS][uu * 4];
                    const float gi = fmaf(acc0[r], DQ, bf2f((unsigned short)pj[0]));
                    const float gf = fmaf(acc1[r], DQ, bf2f((unsigned short)pj[1]));
                    const float gg = fmaf(acc2[r], DQ, bf2f((unsigned short)pj[2]));
                    const float go = fmaf(acc3[r], DQ, bf2f((unsigned short)pj[3]));
                    c[r] = fsig(gf) * c[r] + fsig(gi) * ftanh(gg);
                    hf1 = fsig(go) * ftanh(c[r]);
                } else if (s > 0) {
                    alt1 = prev[hslot + row * 8];
                }
            }
            // HW packed f32->e4m3 (RNE, saturating, branch-free)
            const unsigned int pk = (unsigned int)
                __builtin_amdgcn_cvt_pk_fp8_f32(hf0 * 16.f, hf1 * 16.f, 0, false);
            {
                const int r = r2;
                const int row = (r & 3) + 8 * (r >> 2) + 4 * hq;
                const unsigned char hv = in0 ? (unsigned char)(pk & 0xff) : alt0;
                cur[hslot + row * 8] = hv;
                if (s == w - 1)
                    ho[ksp * 512 + khp * 256 + jp + row * 8] =
                        in0 ? f2bf(hf0) : f2bf(e4m32f(hv) * 0.0625f);
            }
            {
                const int r = r2 + 1;
                const int row = (r & 3) + 8 * (r >> 2) + 4 * hq;
                const unsigned char hv = in1 ? (unsigned char)((pk >> 8) & 0xff) : alt1;
                cur[hslot + row * 8] = hv;
                if (s == w - 1)
                    ho[ksp * 512 + khp * 256 + jp + row * 8] =
                        in1 ? f2bf(hf1) : f2bf(e4m32f(hv) * 0.0625f);
            }
        }

        // ---- commit prefetched row (identical bytes if clamp-duplicate)
        if (nsrc >= 0)
            ((unsigned int*)&Pring[nsrc % PSLOTS][0])[tid] = pref;
        __syncthreads();   // Hbuf + Pring writes visible for next step
    }
}

// ---------------------------------------------------------------- attention, stage 1: partial scores
__global__ __launch_bounds__(192) void attn_scores_kernel(
        const unsigned short* __restrict__ xfrag,
        const unsigned short* __restrict__ hfin,
        float* __restrict__ scores) {
    const int pt = blockIdx.x >> 3, seg = blockIdx.x & 7;
    const int dir = seg >> 2, q = seg & 3;
    const int tid = threadIdx.x;
    const int lane = tid & 63, wv3 = tid >> 6;
    const int pos = lane & 31;
    __shared__ float scp[3][4][32];

    const unsigned short* xb = xfrag + ((size_t)(pt * 48 + 24 * dir)) * 512 + lane * 8;
    const unsigned short* hb0 = hfin + (size_t)(dir * 4) * (NPOS * HH) + (size_t)pt * 12288 + lane * 8;

    float sc4[4] = {0.f, 0.f, 0.f, 0.f};
#pragma unroll
    for (int k = 0; k < 2; ++k) {
        const int ks = q * 6 + wv3 * 2 + k;
        const short8 xv = *(const short8*)(xb + ks * 512);
        float xf[8];
#pragma unroll
        for (int j = 0; j < 8; ++j) xf[j] = bf2f((unsigned short)xv[j]);
#pragma unroll
        for (int wi = 0; wi < 4; ++wi) {
            const short8 hv = *(const short8*)(hb0 + (size_t)wi * (NPOS * HH) + ks * 512);
#pragma unroll
            for (int j = 0; j < 8; ++j)
                sc4[wi] = fmaf(xf[j], bf2f((unsigned short)hv[j]), sc4[wi]);
        }
    }
#pragma unroll
    for (int wi = 0; wi < 4; ++wi) sc4[wi] += __shfl_down(sc4[wi], 32);
    if (lane < 32) {
#pragma unroll
        for (int wi = 0; wi < 4; ++wi) scp[wv3][wi][pos] = sc4[wi];
    }
    __syncthreads();
    if (tid < 32) {
#pragma unroll
        for (int wi = 0; wi < 4; ++wi) {
            const float v = scp[0][wi][tid] + scp[1][wi][tid] + scp[2][wi][tid];
            scores[(((size_t)pt * 8 + seg) * 4 + wi) * 32 + tid] = v;
        }
    }
}

// ---------------------------------------------------------------- attention, stage 2: softmax + output
__global__ __launch_bounds__(192) void attn_out2_kernel(
        const unsigned short* __restrict__ xfrag,
        const unsigned short* __restrict__ hfin,
        const float* __restrict__ scores,
        const float* __restrict__ lin_w,
        float* __restrict__ out) {
    const int pt = blockIdx.x >> 3, seg = blockIdx.x & 7;
    const int dir = seg >> 2, q = seg & 3;
    const int tid = threadIdx.x;
    const int lane = tid & 63, wv3 = tid >> 6;
    const int pos = lane & 31, kh = lane >> 5;
    const float inv_sqrt_d = 0.03608439182435161f;
    __shared__ float redp[3][32][10];

    float s[4];
#pragma unroll
    for (int wi = 0; wi < 4; ++wi) {
        float v = 0.f;
#pragma unroll
        for (int s2 = 0; s2 < 8; ++s2)
            v += scores[(((size_t)pt * 8 + s2) * 4 + wi) * 32 + pos];
        s[wi] = v * inv_sqrt_d;
    }
    float mx = fmaxf(fmaxf(s[0], s[1]), fmaxf(s[2], s[3]));
    float denom = 0.f;
    float aw[4];
#pragma unroll
    for (int wi = 0; wi < 4; ++wi) { aw[wi] = __expf(s[wi] - mx); denom += aw[wi]; }
    const float rd = __builtin_amdgcn_rcpf(denom);
#pragma unroll
    for (int wi = 0; wi < 4; ++wi) aw[wi] *= rd;

    const unsigned short* xb = xfrag + ((size_t)(pt * 48 + 24 * dir)) * 512 + lane * 8;
    const unsigned short* hb0 = hfin + (size_t)(dir * 4) * (NPOS * HH) + (size_t)pt * 12288 + lane * 8;

    float rp[9];
#pragma unroll
    for (int r = 0; r < 9; ++r) rp[r] = 0.f;
#pragma unroll
    for (int k = 0; k < 2; ++k) {
        const int ks = q * 6 + wv3 * 2 + k;
        const short8 xv = *(const short8*)(xb + ks * 512);
        float ov[8];
#pragma unroll
        for (int j = 0; j < 8; ++j) ov[j] = bf2f((unsigned short)xv[j]);
#pragma unroll
        for (int wi = 0; wi < 4; ++wi) {
            const short8 hv = *(const short8*)(hb0 + (size_t)wi * (NPOS * HH) + ks * 512);
#pragma unroll
            for (int j = 0; j < 8; ++j)
                ov[j] = fmaf(aw[wi], bf2f((unsigned short)hv[j]), ov[j]);
        }
        const int dbase = dir * 384 + ks * 16 + kh * 8;
#pragma unroll
        for (int r = 0; r < 9; ++r) {
            const float4 lw0 = *(const float4*)(lin_w + r * DD + dbase);
            const float4 lw1 = *(const float4*)(lin_w + r * DD + dbase + 4);
            rp[r] += ov[0] * lw0.x + ov[1] * lw0.y + ov[2] * lw0.z + ov[3] * lw0.w
                   + ov[4] * lw1.x + ov[5] * lw1.y + ov[6] * lw1.z + ov[7] * lw1.w;
        }
    }
#pragma unroll
    for (int r = 0; r < 9; ++r) rp[r] += __shfl_down(rp[r], 32);
    if (lane < 32) {
#pragma unroll
        for (int r = 0; r < 9; ++r) redp[wv3][pos][r] = rp[r];
    }
    __syncthreads();
    if (tid < 96) {
#pragma unroll
        for (int e = 0; e < 3; ++e) {
            const int flat = tid * 3 + e;
            const int p2 = flat / 9, r = flat % 9;
            const float sum = redp[0][p2][r] + redp[1][p2][r] + redp[2][p2][r];
            atomicAdd(&out[(size_t)(pt * 32 + p2) * NLIN + r], sum);
        }
    }
}

// ---------------------------------------------------------------- launch
extern "C" void kernel_launch(void* const* d_in, const int* in_sizes, int n_in,
                              void* d_out, int out_size, void* d_ws, size_t ws_size,
                              hipStream_t stream) {
    (void)in_sizes; (void)n_in; (void)out_size; (void)ws_size;
    const float* seq   = (const float*)d_in[0];
    const int*   valid = (const int*)d_in[1];
    const float* wih_f = (const float*)d_in[2];
    const float* whh_f = (const float*)d_in[3];
    const float* bih_f = (const float*)d_in[4];
    const float* bhh_f = (const float*)d_in[5];
    const float* wih_b = (const float*)d_in[6];
    const float* whh_b = (const float*)d_in[7];
    const float* bih_b = (const float*)d_in[8];
    const float* bhh_b = (const float*)d_in[9];
    const float* lin_w = (const float*)d_in[10];
    const float* lin_b = (const float*)d_in[11];
    float* out = (float*)d_out;

    // workspace layout (~61.5 MB; wfhh region holds fp8 bytes, underused)
    unsigned short* xfrag = (unsigned short*)d_ws;                 // 786432 bf16
    unsigned short* proj  = xfrag + (size_t)NPOS * DD;             // 12582912 bf16
    unsigned short* wfhh  = proj + (size_t)NPOS * PROJ_N;          // region (fp8 uses half)
    unsigned short* wfih  = wfhh + (size_t)4718592;                // 9437184 bf16
    unsigned short* hfin  = wfih + (size_t)9437184;                // 3145728 bf16
    float* scores = (float*)(hfin + (size_t)3145728);              // 128 KB

    prep_kernel<<<897, 256, 0, stream>>>(seq, valid, xfrag,
                                         wih_f, wih_b, wfih,
                                         whh_f, whh_b, (unsigned char*)wfhh,
                                         lin_b, out);
    proj_mfma<<<768, 256, 0, stream>>>(xfrag, wfih, bih_f, bhh_f, bih_b, bhh_b, proj);
    lstm_fused<<<256, 768, 0, stream>>>((const unsigned char*)wfhh, proj, hfin);
    attn_scores_kernel<<<256, 192, 0, stream>>>(xfrag, hfin, scores);
    attn_out2_kernel<<<256, 192, 0, stream>>>(xfrag, hfin, scores, lin_w, out);
}